// Round 1
// baseline (39661.630 us; speedup 1.0000x reference)
//
#include <hip/hip_runtime.h>
#include <cmath>

// Problem constants
#define BATCH 8
#define SEQ   512
#define EMB   512
#define HEADS 8
#define DK    64
#define FF    2048
#define VOCAB 32000
#define TOK   (BATCH * SEQ)   // 4096 rows
#define INV_SCALE 0.125f      // 1/sqrt(64)

// ---------------------------------------------------------------------------
// Embedding lookup + positional encoding (faithful f32 like the jax ref)
// out[row, d] = table[tok[row], d] + pe(s, d),  s = row % SEQ
// pe: ang = s / 10000^(2d/512); even d -> sin, odd d -> cos
// ---------------------------------------------------------------------------
__global__ __launch_bounds__(256) void embed_pe_kernel(
    const int* __restrict__ tok, const float* __restrict__ table,
    float* __restrict__ out)
{
    int idx = blockIdx.x * 256 + threadIdx.x;      // < TOK*EMB = 2M
    int d   = idx & (EMB - 1);
    int row = idx >> 9;                            // EMB = 512 = 2^9
    int s   = row & (SEQ - 1);                     // SEQ = 512
    float p   = powf(10000.0f, (2.0f * (float)d) * (1.0f / (float)EMB));
    float ang = (float)s / p;
    float pe  = ((d & 1) == 0) ? sinf(ang) : cosf(ang);
    out[idx] = table[(size_t)tok[row] * EMB + d] + pe;
}

// ---------------------------------------------------------------------------
// Generic GEMM: C[M,N] = A[M,K] @ W[N,K]^T (+ bias[n]) (optional ReLU)
// 64x64 tile, BK=16, 256 threads, 4x4 accum per thread. All dims multiples.
// ---------------------------------------------------------------------------
template<bool HASBIAS, bool RELU>
__global__ __launch_bounds__(256) void gemm_tn(
    const float* __restrict__ A, const float* __restrict__ W,
    const float* __restrict__ bias, float* __restrict__ C,
    int M, int N, int K)
{
    __shared__ float As[16][64];
    __shared__ float Bs[16][64];
    const int tid = threadIdx.x;
    const int tx  = tid & 15;          // n-direction
    const int ty  = tid >> 4;          // m-direction
    const int m0  = blockIdx.y << 6;
    const int n0  = blockIdx.x << 6;
    const int lrow = tid >> 2;         // 0..63
    const int lcol = (tid & 3) << 2;   // 0,4,8,12

    const float* Aload = A + (size_t)(m0 + lrow) * K + lcol;
    const float* Wload = W + (size_t)(n0 + lrow) * K + lcol;

    float acc[4][4] = {};

    for (int k0 = 0; k0 < K; k0 += 16) {
        float4 a4 = *(const float4*)(Aload + k0);
        float4 w4 = *(const float4*)(Wload + k0);
        As[lcol + 0][lrow] = a4.x; As[lcol + 1][lrow] = a4.y;
        As[lcol + 2][lrow] = a4.z; As[lcol + 3][lrow] = a4.w;
        Bs[lcol + 0][lrow] = w4.x; Bs[lcol + 1][lrow] = w4.y;
        Bs[lcol + 2][lrow] = w4.z; Bs[lcol + 3][lrow] = w4.w;
        __syncthreads();
#pragma unroll
        for (int kk = 0; kk < 16; ++kk) {
            float4 av = *(const float4*)&As[kk][ty << 2];
            float4 bv = *(const float4*)&Bs[kk][tx << 2];
            float a[4] = {av.x, av.y, av.z, av.w};
            float b[4] = {bv.x, bv.y, bv.z, bv.w};
#pragma unroll
            for (int i = 0; i < 4; ++i)
#pragma unroll
                for (int j = 0; j < 4; ++j)
                    acc[i][j] = fmaf(a[i], b[j], acc[i][j]);
        }
        __syncthreads();
    }

#pragma unroll
    for (int i = 0; i < 4; ++i) {
        const int m = m0 + (ty << 2) + i;
#pragma unroll
        for (int j = 0; j < 4; ++j) {
            const int n = n0 + (tx << 2) + j;
            float v = acc[i][j];
            if (HASBIAS) v += bias[n];
            if (RELU)    v = fmaxf(v, 0.0f);
            C[(size_t)m * N + n] = v;
        }
    }
}

// ---------------------------------------------------------------------------
// Attention: one block per (q, h, b). scores = (Q.K^T + mask)/SCALE,
// softmax over k, ctx[row, h*64+d] = sum_k w[k] * V[k,d].
// Q/K/V given by base ptr + row-stride + per-head col stride (offsets folded
// into the base pointers host-side).
// ---------------------------------------------------------------------------
__global__ __launch_bounds__(256) void attn_kernel(
    const float* __restrict__ Qb, int q_rs, int q_hs,
    const float* __restrict__ Kb, int k_rs, int k_hs,
    const float* __restrict__ Vb, int v_rs, int v_hs,
    const float* __restrict__ addmask, int causal,
    float* __restrict__ ctx, int SQ, int SK)
{
    const int q = blockIdx.x, h = blockIdx.y, b = blockIdx.z;
    const int t = threadIdx.x;
    __shared__ float sQ[DK];
    __shared__ float sc[SEQ];
    __shared__ float red[256];

    const float* Qrow = Qb + (size_t)(b * SQ + q) * q_rs + h * q_hs;
    if (t < DK) sQ[t] = Qrow[t];
    __syncthreads();

    const float4* q4 = (const float4*)sQ;
    for (int k = t; k < SK; k += 256) {
        const float4* Krow = (const float4*)(Kb + (size_t)(b * SK + k) * k_rs + h * k_hs);
        float dot = 0.0f;
#pragma unroll
        for (int i = 0; i < DK / 4; ++i) {
            float4 kk = Krow[i], qq = q4[i];
            dot = fmaf(qq.x, kk.x, dot);
            dot = fmaf(qq.y, kk.y, dot);
            dot = fmaf(qq.z, kk.z, dot);
            dot = fmaf(qq.w, kk.w, dot);
        }
        float m = addmask ? addmask[(size_t)b * SK + k] : 0.0f;
        if (causal && k > q) m = -INFINITY;
        sc[k] = (dot + m) * INV_SCALE;
    }
    __syncthreads();

    // max reduce
    float lm = -INFINITY;
    for (int k = t; k < SK; k += 256) lm = fmaxf(lm, sc[k]);
    red[t] = lm; __syncthreads();
    for (int o = 128; o > 0; o >>= 1) {
        if (t < o) red[t] = fmaxf(red[t], red[t + o]);
        __syncthreads();
    }
    const float M = red[0];
    __syncthreads();

    // exp + sum reduce
    float ls = 0.0f;
    for (int k = t; k < SK; k += 256) {
        float e = expf(sc[k] - M);
        sc[k] = e;
        ls += e;
    }
    red[t] = ls; __syncthreads();
    for (int o = 128; o > 0; o >>= 1) {
        if (t < o) red[t] += red[t + o];
        __syncthreads();
    }
    const float inv = 1.0f / red[0];
    __syncthreads();

    // ctx = (sum_k e_k * V[k,:]) * inv   — 4 partial groups over k
    const int d = t & 63, grp = t >> 6;
    float part = 0.0f;
    for (int k = grp; k < SK; k += 4) {
        float v = Vb[(size_t)(b * SK + k) * v_rs + h * v_hs + d];
        part = fmaf(sc[k], v, part);
    }
    red[t] = part; __syncthreads();
    if (t < 64) {
        float ssum = red[t] + red[t + 64] + red[t + 128] + red[t + 192];
        ctx[(size_t)(b * SQ + q) * EMB + h * DK + d] = ssum * inv;
    }
}

// ---------------------------------------------------------------------------
// x[row,:] = LayerNorm(x[row,:] + delta[row,:]) * g + b   (row length 512)
// ---------------------------------------------------------------------------
__global__ __launch_bounds__(256) void add_ln_kernel(
    float* __restrict__ x, const float* __restrict__ delta,
    const float* __restrict__ g, const float* __restrict__ b)
{
    const int row = blockIdx.x;
    const int t = threadIdx.x;
    __shared__ float red[256];
    const size_t base = (size_t)row * EMB;

    float v0 = x[base + t]       + delta[base + t];
    float v1 = x[base + 256 + t] + delta[base + 256 + t];

    red[t] = v0 + v1; __syncthreads();
    for (int o = 128; o > 0; o >>= 1) {
        if (t < o) red[t] += red[t + o];
        __syncthreads();
    }
    const float mean = red[0] * (1.0f / (float)EMB);
    __syncthreads();

    const float a0 = v0 - mean, a1 = v1 - mean;
    red[t] = a0 * a0 + a1 * a1; __syncthreads();
    for (int o = 128; o > 0; o >>= 1) {
        if (t < o) red[t] += red[t + o];
        __syncthreads();
    }
    const float inv = 1.0f / sqrtf(red[0] * (1.0f / (float)EMB) + 1e-5f);

    x[base + t]       = a0 * inv * g[t]       + b[t];
    x[base + 256 + t] = a1 * inv * g[256 + t] + b[256 + t];
}

// ---------------------------------------------------------------------------
// Row softmax over VOCAB (in place). One block per row, online max/sum.
// ---------------------------------------------------------------------------
__global__ __launch_bounds__(256) void softmax_vocab_kernel(float* __restrict__ X)
{
    const int row = blockIdx.x;
    const int t = threadIdx.x;
    __shared__ float rm[256], rs[256];
    float* x = X + (size_t)row * VOCAB;

    float m = -INFINITY, s = 0.0f;
    for (int k = t; k < VOCAB; k += 256) {
        float v = x[k];
        if (v > m) { s = s * expf(m - v) + 1.0f; m = v; }
        else       { s += expf(v - m); }
    }
    rm[t] = m; rs[t] = s; __syncthreads();
    for (int o = 128; o > 0; o >>= 1) {
        if (t < o) {
            float m1 = rm[t], m2 = rm[t + o];
            float s1 = rs[t], s2 = rs[t + o];
            float MM = fmaxf(m1, m2);
            rs[t] = s1 * expf(m1 - MM) + s2 * expf(m2 - MM);
            rm[t] = MM;
        }
        __syncthreads();
    }
    const float M = rm[0];
    const float inv = 1.0f / rs[0];
    for (int k = t; k < VOCAB; k += 256) x[k] = expf(x[k] - M) * inv;
}

// ---------------------------------------------------------------------------
// Host orchestration
// ---------------------------------------------------------------------------
static inline void launch_gemm(const float* A, const float* W, const float* bias,
                               float* C, int M, int N, int K, bool relu,
                               hipStream_t stream)
{
    dim3 grid((unsigned)(N / 64), (unsigned)(M / 64));
    if (bias) {
        if (relu) gemm_tn<true, true ><<<grid, 256, 0, stream>>>(A, W, bias, C, M, N, K);
        else      gemm_tn<true, false><<<grid, 256, 0, stream>>>(A, W, bias, C, M, N, K);
    } else {
        gemm_tn<false, false><<<grid, 256, 0, stream>>>(A, W, nullptr, C, M, N, K);
    }
}

extern "C" void kernel_launch(void* const* d_in, const int* in_sizes, int n_in,
                              void* d_out, int out_size, void* d_ws, size_t ws_size,
                              hipStream_t stream)
{
    const int*   enc      = (const int*)  d_in[0];
    const int*   dec      = (const int*)  d_in[1];
    const float* enc_mask = (const float*)d_in[2];
    const float* dec_mask = (const float*)d_in[3];
    // d_in[4], d_in[5]: enc_num/dec_num == 6 (compile-time constants)
    const float* emb    = (const float*)d_in[6];
    const float* w_qkv  = (const float*)d_in[7];
    const float* w_lin  = (const float*)d_in[8];
    const float* b_lin  = (const float*)d_in[9];
    const float* w_ff1  = (const float*)d_in[10];
    const float* b_ff1  = (const float*)d_in[11];
    const float* w_ff2  = (const float*)d_in[12];
    const float* b_ff2  = (const float*)d_in[13];
    const float* w_out  = (const float*)d_in[14];
    const float* b_out  = (const float*)d_in[15];
    const float* ln_e1g = (const float*)d_in[16];
    const float* ln_e1b = (const float*)d_in[17];
    const float* ln_e2g = (const float*)d_in[18];
    const float* ln_e2b = (const float*)d_in[19];
    const float* ln_d1g = (const float*)d_in[20];
    const float* ln_d1b = (const float*)d_in[21];
    const float* ln_d2g = (const float*)d_in[22];
    const float* ln_d2b = (const float*)d_in[23];
    const float* ln_d3g = (const float*)d_in[24];
    const float* ln_d3b = (const float*)d_in[25];

    float* out = (float*)d_out;

    // Workspace layout. x_d must survive until the final vocab GEMM, so it
    // always lives in d_ws. Everything else is dead before the final GEMM
    // and can fall back into d_out if d_ws is small.
    const size_t sz_x   = (size_t)TOK * EMB * sizeof(float);   // 8 MB
    const size_t sz_qkv = (size_t)TOK * 3 * EMB * sizeof(float); // 25 MB
    const size_t sz_ff  = (size_t)TOK * FF * sizeof(float);    // 33.5 MB
    const size_t need   = 2 * sz_x + 2 * sz_qkv + 2 * sz_x + sz_ff;

    char* wsp = (char*)d_ws;
    float* x_d_buf = (float*)wsp; wsp += sz_x;
    float *x_e, *qkv, *ekv, *ctxb, *tmpb, *ffb;
    if (ws_size >= need) {
        x_e  = (float*)wsp; wsp += sz_x;
        qkv  = (float*)wsp; wsp += sz_qkv;
        ekv  = (float*)wsp; wsp += sz_qkv;
        ctxb = (float*)wsp; wsp += sz_x;
        tmpb = (float*)wsp; wsp += sz_x;
        ffb  = (float*)wsp;
    } else {
        char* op = (char*)d_out;   // scratch inside d_out; dead before final GEMM
        x_e  = (float*)op; op += sz_x;
        qkv  = (float*)op; op += sz_qkv;
        ekv  = (float*)op; op += sz_qkv;
        ctxb = (float*)op; op += sz_x;
        tmpb = (float*)op; op += sz_x;
        ffb  = (float*)op;
    }

    const dim3 attn_grid(SEQ, HEADS, BATCH);
    const int  embed_blocks = (TOK * EMB) / 256;

    // Embedding + positional encoding
    embed_pe_kernel<<<embed_blocks, 256, 0, stream>>>(enc, emb, x_e);
    embed_pe_kernel<<<embed_blocks, 256, 0, stream>>>(dec, emb, x_d_buf);

    // ---------------- Encoder (6 layers) ----------------
    for (int l = 0; l < 6; ++l) {
        launch_gemm(x_e, w_qkv, nullptr, qkv, TOK, 3 * EMB, EMB, false, stream);
        attn_kernel<<<attn_grid, 256, 0, stream>>>(
            qkv,        3 * EMB, 3 * DK,       // Q: col h*192 + d
            qkv + DK,   3 * EMB, 3 * DK,       // K: col h*192 + 64 + d
            qkv + 2*DK, 3 * EMB, 3 * DK,       // V: col h*192 + 128 + d
            enc_mask, 0, ctxb, SEQ, SEQ);
        launch_gemm(ctxb, w_lin, b_lin, tmpb, TOK, EMB, EMB, false, stream);
        add_ln_kernel<<<TOK, 256, 0, stream>>>(x_e, tmpb, ln_e1g, ln_e1b);
        launch_gemm(x_e, w_ff1, b_ff1, ffb, TOK, FF, EMB, true, stream);
        launch_gemm(ffb, w_ff2, b_ff2, tmpb, TOK, EMB, FF, false, stream);
        add_ln_kernel<<<TOK, 256, 0, stream>>>(x_e, tmpb, ln_e2g, ln_e2b);
    }

    // Encoder K/V for cross-attention
    launch_gemm(x_e, w_qkv, nullptr, ekv, TOK, 3 * EMB, EMB, false, stream);

    // ---------------- Decoder (6 layers) ----------------
    for (int l = 0; l < 6; ++l) {
        // self-attention (causal + dec_mask)
        launch_gemm(x_d_buf, w_qkv, nullptr, qkv, TOK, 3 * EMB, EMB, false, stream);
        attn_kernel<<<attn_grid, 256, 0, stream>>>(
            qkv,        3 * EMB, 3 * DK,
            qkv + DK,   3 * EMB, 3 * DK,
            qkv + 2*DK, 3 * EMB, 3 * DK,
            dec_mask, 1, ctxb, SEQ, SEQ);
        launch_gemm(ctxb, w_lin, b_lin, tmpb, TOK, EMB, EMB, false, stream);
        add_ln_kernel<<<TOK, 256, 0, stream>>>(x_d_buf, tmpb, ln_d1g, ln_d1b);

        // cross-attention: dq = (x_d @ w_qkv.T)[:, :512] — head stride 64
        launch_gemm(x_d_buf, w_qkv, nullptr, qkv, TOK, EMB, EMB, false, stream);
        attn_kernel<<<attn_grid, 256, 0, stream>>>(
            qkv,          EMB,     DK,          // dq: col h*64 + d, row stride 512
            ekv + DK,     3 * EMB, 3 * DK,      // ek
            ekv + 2*DK,   3 * EMB, 3 * DK,      // ev
            enc_mask, 0, ctxb, SEQ, SEQ);
        launch_gemm(ctxb, w_lin, b_lin, tmpb, TOK, EMB, EMB, false, stream);
        add_ln_kernel<<<TOK, 256, 0, stream>>>(x_d_buf, tmpb, ln_d2g, ln_d2b);

        // FFN
        launch_gemm(x_d_buf, w_ff1, b_ff1, ffb, TOK, FF, EMB, true, stream);
        launch_gemm(ffb, w_ff2, b_ff2, tmpb, TOK, EMB, FF, false, stream);
        add_ln_kernel<<<TOK, 256, 0, stream>>>(x_d_buf, tmpb, ln_d3g, ln_d3b);
    }

    // ---------------- Output projection + softmax ----------------
    launch_gemm(x_d_buf, w_out, b_out, out, TOK, VOCAB, EMB, false, stream);
    softmax_vocab_kernel<<<TOK, 256, 0, stream>>>(out);
}